// Round 1
// baseline (1949.187 us; speedup 1.0000x reference)
//
#include <hip/hip_runtime.h>
#include <hip/hip_bf16.h>
#include <math.h>

#define TSEQ   2048
#define BATCH  4
#define DIM    1024
#define NH     16
#define HD     64
#define MTOT   (BATCH*TSEQ)   // 8192

// ---------------------------------------------------------------------------
// GEMM: C[M,N] = A[M,K] @ B[K,N] (+bias).  BM=BN=128, BK=16, 256 thr, 8x8/thr
// (split 4+4 halves so LDS reads stay 2-way / broadcast).
// ---------------------------------------------------------------------------
__global__ __launch_bounds__(256, 2)
void gemm128_f32(const float* __restrict__ A, const float* __restrict__ B,
                 const float* __restrict__ bias, float* __restrict__ C,
                 const int M, const int N, const int K)
{
    __shared__ float As[16][128];   // [k][m] (transposed at staging)
    __shared__ float Bs[16][128];   // [k][n]

    const int t  = threadIdx.x;
    const int tx = t & 15;
    const int ty = t >> 4;
    const int m0 = blockIdx.x * 128;
    const int n0 = blockIdx.y * 128;

    float acc[8][8];
#pragma unroll
    for (int i = 0; i < 8; ++i)
#pragma unroll
        for (int j = 0; j < 8; ++j) acc[i][j] = 0.f;

    const int ar0 = t >> 2;   // 0..63  (A row within tile, +64 second pass)
    const int ac4 = t & 3;    // 0..3   (A float4-col within BK=16)
    const int br0 = t >> 5;   // 0..7   (B row within BK, +8 second pass)
    const int bc4 = t & 31;   // 0..31  (B float4-col within 128)

    for (int kt = 0; kt < K; kt += 16) {
        // stage A (transpose [m][k] -> [k][m])
#pragma unroll
        for (int p = 0; p < 2; ++p) {
            const int r = ar0 + p*64;
            const float4 a = *reinterpret_cast<const float4*>(
                &A[(size_t)(m0 + r)*K + kt + ac4*4]);
            As[ac4*4+0][r] = a.x;
            As[ac4*4+1][r] = a.y;
            As[ac4*4+2][r] = a.z;
            As[ac4*4+3][r] = a.w;
        }
        // stage B (direct)
#pragma unroll
        for (int p = 0; p < 2; ++p) {
            const int r = br0 + p*8;
            const float4 b = *reinterpret_cast<const float4*>(
                &B[(size_t)(kt + r)*N + n0 + bc4*4]);
            *reinterpret_cast<float4*>(&Bs[r][bc4*4]) = b;
        }
        __syncthreads();

#pragma unroll
        for (int kk = 0; kk < 16; ++kk) {
            float ar[8], br[8];
            *reinterpret_cast<float4*>(&ar[0]) = *reinterpret_cast<float4*>(&As[kk][ty*4]);
            *reinterpret_cast<float4*>(&ar[4]) = *reinterpret_cast<float4*>(&As[kk][ty*4+64]);
            *reinterpret_cast<float4*>(&br[0]) = *reinterpret_cast<float4*>(&Bs[kk][tx*4]);
            *reinterpret_cast<float4*>(&br[4]) = *reinterpret_cast<float4*>(&Bs[kk][tx*4+64]);
#pragma unroll
            for (int i = 0; i < 8; ++i)
#pragma unroll
                for (int j = 0; j < 8; ++j)
                    acc[i][j] = fmaf(ar[i], br[j], acc[i][j]);
        }
        __syncthreads();
    }

    // epilogue: rows m0 + ih*64 + ty*4+i, cols n0 + jh*64 + tx*4+j
#pragma unroll
    for (int jh = 0; jh < 2; ++jh) {
        float4 b4 = make_float4(0.f, 0.f, 0.f, 0.f);
        if (bias) b4 = *reinterpret_cast<const float4*>(&bias[n0 + jh*64 + tx*4]);
#pragma unroll
        for (int ih = 0; ih < 2; ++ih)
#pragma unroll
            for (int i = 0; i < 4; ++i) {
                const int row = m0 + ih*64 + ty*4 + i;
                float4 o;
                o.x = acc[ih*4+i][jh*4+0] + b4.x;
                o.y = acc[ih*4+i][jh*4+1] + b4.y;
                o.z = acc[ih*4+i][jh*4+2] + b4.z;
                o.w = acc[ih*4+i][jh*4+3] + b4.w;
                *reinterpret_cast<float4*>(&C[(size_t)row*N + n0 + jh*64 + tx*4]) = o;
            }
    }
}

// ---------------------------------------------------------------------------
// Flash attention (causal). One block per (q-tile of 64 rows, b*16+h).
// 256 threads; thread (ty,tx) owns S/ctx micro-tile rows ty*4+i, cols tx*4+j.
// LDS rows are 64 floats (== 2*32 banks) so same-column reads across rows
// would be 16-way conflicts -> XOR-swizzle the float4-column by (row>>2)&15.
// ---------------------------------------------------------------------------
__device__ __forceinline__ int swz(int r, int c4) {
    return r*64 + ((c4 ^ (r >> 2)) & 15)*4;
}

__global__ __launch_bounds__(256, 2)
void attn_f32(const float* __restrict__ Q, const float* __restrict__ Km,
              const float* __restrict__ V, float* __restrict__ O)
{
    __shared__ float Qs[64*64];
    __shared__ float Ks[64*64];
    __shared__ float Vs[64*64];
    __shared__ float Ps[64*64];

    const int t  = threadIdx.x;
    const int tx = t & 15;
    const int ty = t >> 4;
    const int qt = blockIdx.x;       // 0..31
    const int bh = blockIdx.y;       // b*16 + h
    const int b  = bh >> 4;
    const int h  = bh & 15;
    const int q0 = qt * 64;

    const size_t rowbase = (size_t)b * TSEQ;
    const int    cbase   = h * HD;

    // stage Q tile, pre-scaled by 1/sqrt(HD)
    {
        const int rr = t >> 4, c4 = t & 15;
#pragma unroll
        for (int it = 0; it < 4; ++it) {
            const int r = rr + it*16;
            float4 q = *reinterpret_cast<const float4*>(
                &Q[(rowbase + q0 + r)*DIM + cbase + c4*4]);
            q.x *= 0.125f; q.y *= 0.125f; q.z *= 0.125f; q.w *= 0.125f;
            *reinterpret_cast<float4*>(&Qs[swz(r, c4)]) = q;
        }
    }

    float m_i[4], l_i[4], ctx[4][4];
#pragma unroll
    for (int i = 0; i < 4; ++i) {
        m_i[i] = -INFINITY; l_i[i] = 0.f;
#pragma unroll
        for (int j = 0; j < 4; ++j) ctx[i][j] = 0.f;
    }

    for (int kv = 0; kv <= qt; ++kv) {
        __syncthreads();   // protect Ks/Vs/Ps from previous iteration readers
        {
            const int rr = t >> 4, c4 = t & 15;
#pragma unroll
            for (int it = 0; it < 4; ++it) {
                const int r = rr + it*16;
                const size_t g = (rowbase + kv*64 + r)*DIM + cbase + c4*4;
                const float4 kk4 = *reinterpret_cast<const float4*>(&Km[g]);
                *reinterpret_cast<float4*>(&Ks[swz(r, c4)]) = kk4;
                const float4 vv4 = *reinterpret_cast<const float4*>(&V[g]);
                *reinterpret_cast<float4*>(&Vs[r*64 + c4*4]) = vv4;
            }
        }
        __syncthreads();

        // S = Qs @ Ks^T (over d)
        float s[4][4];
#pragma unroll
        for (int i = 0; i < 4; ++i)
#pragma unroll
            for (int j = 0; j < 4; ++j) s[i][j] = 0.f;

        for (int c4 = 0; c4 < 16; ++c4) {
            float qa[4][4], ka[4][4];
#pragma unroll
            for (int i = 0; i < 4; ++i)
                *reinterpret_cast<float4*>(qa[i]) =
                    *reinterpret_cast<float4*>(&Qs[swz(ty*4+i, c4)]);
#pragma unroll
            for (int j = 0; j < 4; ++j)
                *reinterpret_cast<float4*>(ka[j]) =
                    *reinterpret_cast<float4*>(&Ks[swz(tx*4+j, c4)]);
#pragma unroll
            for (int i = 0; i < 4; ++i)
#pragma unroll
                for (int j = 0; j < 4; ++j)
#pragma unroll
                    for (int c = 0; c < 4; ++c)
                        s[i][j] = fmaf(qa[i][c], ka[j][c], s[i][j]);
        }

        if (kv == qt) {   // diagonal tile: mask k > q
#pragma unroll
            for (int i = 0; i < 4; ++i)
#pragma unroll
                for (int j = 0; j < 4; ++j)
                    if (tx*4+j > ty*4+i) s[i][j] = -INFINITY;
        }

        // online softmax (row groups = 16 lanes sharing ty)
#pragma unroll
        for (int i = 0; i < 4; ++i) {
            float mx = fmaxf(fmaxf(s[i][0], s[i][1]), fmaxf(s[i][2], s[i][3]));
            mx = fmaxf(mx, __shfl_xor(mx, 1));
            mx = fmaxf(mx, __shfl_xor(mx, 2));
            mx = fmaxf(mx, __shfl_xor(mx, 4));
            mx = fmaxf(mx, __shfl_xor(mx, 8));
            const float mnew  = fmaxf(m_i[i], mx);
            const float scale = __expf(m_i[i] - mnew);
            float4 p;
            p.x = __expf(s[i][0] - mnew);
            p.y = __expf(s[i][1] - mnew);
            p.z = __expf(s[i][2] - mnew);
            p.w = __expf(s[i][3] - mnew);
            float rs = p.x + p.y + p.z + p.w;
            rs += __shfl_xor(rs, 1);
            rs += __shfl_xor(rs, 2);
            rs += __shfl_xor(rs, 4);
            rs += __shfl_xor(rs, 8);
            l_i[i] = l_i[i]*scale + rs;
            m_i[i] = mnew;
#pragma unroll
            for (int j = 0; j < 4; ++j) ctx[i][j] *= scale;
            *reinterpret_cast<float4*>(&Ps[swz(ty*4+i, tx)]) = p;
        }
        __syncthreads();

        // ctx += P @ V
        for (int k4 = 0; k4 < 16; ++k4) {
            float pa[4][4], va[4][4];
#pragma unroll
            for (int i = 0; i < 4; ++i)
                *reinterpret_cast<float4*>(pa[i]) =
                    *reinterpret_cast<float4*>(&Ps[swz(ty*4+i, k4)]);
#pragma unroll
            for (int kk = 0; kk < 4; ++kk)
                *reinterpret_cast<float4*>(va[kk]) =
                    *reinterpret_cast<float4*>(&Vs[(k4*4+kk)*64 + tx*4]);
#pragma unroll
            for (int i = 0; i < 4; ++i)
#pragma unroll
                for (int j = 0; j < 4; ++j)
#pragma unroll
                    for (int kk = 0; kk < 4; ++kk)
                        ctx[i][j] = fmaf(pa[i][kk], va[kk][j], ctx[i][j]);
        }
    }

    // normalize + write ctx (plain [m][DIM] layout)
#pragma unroll
    for (int i = 0; i < 4; ++i) {
        const float inv = 1.f / l_i[i];
        float4 o;
        o.x = ctx[i][0]*inv; o.y = ctx[i][1]*inv;
        o.z = ctx[i][2]*inv; o.w = ctx[i][3]*inv;
        *reinterpret_cast<float4*>(
            &O[(rowbase + q0 + ty*4+i)*DIM + cbase + tx*4]) = o;
    }
}

// ---------------------------------------------------------------------------
extern "C" void kernel_launch(void* const* d_in, const int* in_sizes, int n_in,
                              void* d_out, int out_size, void* d_ws, size_t ws_size,
                              hipStream_t stream)
{
    const float* x  = (const float*)d_in[0];
    const float* Wq = (const float*)d_in[1];
    const float* Wk = (const float*)d_in[2];
    const float* Wv = (const float*)d_in[3];
    const float* Wo = (const float*)d_in[4];
    const float* bo = (const float*)d_in[5];
    float* out = (float*)d_out;

    // ws: q | k | v  (fp32, MTOT*DIM each = 32 MB each, 96 MB total).
    // ctx is written back into the q buffer: each attn block reads only its own
    // Q rows/head-cols (before its first barrier) and writes exactly those
    // elements (after its last barrier) -> no cross-block hazard.
    float* q_ws = (float*)d_ws;
    float* k_ws = q_ws + (size_t)MTOT * DIM;
    float* v_ws = k_ws + (size_t)MTOT * DIM;

    dim3 gg(MTOT/128, DIM/128);
    gemm128_f32<<<gg, 256, 0, stream>>>(x, Wq, nullptr, q_ws, MTOT, DIM, DIM);
    gemm128_f32<<<gg, 256, 0, stream>>>(x, Wk, nullptr, k_ws, MTOT, DIM, DIM);
    gemm128_f32<<<gg, 256, 0, stream>>>(x, Wv, nullptr, v_ws, MTOT, DIM, DIM);

    attn_f32<<<dim3(TSEQ/64, BATCH*NH), 256, 0, stream>>>(q_ws, k_ws, v_ws, q_ws);

    gemm128_f32<<<gg, 256, 0, stream>>>(q_ws, Wo, bo, out, MTOT, DIM, DIM);
}

// Round 3
// 450.805 us; speedup vs baseline: 4.3238x; 4.3238x over previous
//
#include <hip/hip_runtime.h>
#include <hip/hip_bf16.h>
#include <math.h>

#define TSEQ   2048
#define BATCH  4
#define DIM    1024
#define NH     16
#define HD     64
#define MTOT   (BATCH*TSEQ)   // 8192

typedef __attribute__((ext_vector_type(8))) short bf16x8;   // 8 bf16 = 4 VGPRs
typedef __attribute__((ext_vector_type(4))) float f32x4;

__device__ __forceinline__ unsigned short f2bf(float f) {
    unsigned int b = __float_as_uint(f);
    b = (b + 0x7fffu + ((b >> 16) & 1u)) >> 16;   // RTN-even
    return (unsigned short)b;
}

// ---------------------------------------------------------------------------
// x fp32 -> bf16, 8 elems/thread
// ---------------------------------------------------------------------------
__global__ __launch_bounds__(256)
void cvt_x(const float* __restrict__ in, unsigned short* __restrict__ out, int n8)
{
    int i = blockIdx.x * 256 + threadIdx.x;
    if (i >= n8) return;
    const float4* p = (const float4*)in + 2 * (size_t)i;
    float4 a = p[0], b = p[1];
    bf16x8 o;
    o[0] = (short)f2bf(a.x); o[1] = (short)f2bf(a.y);
    o[2] = (short)f2bf(a.z); o[3] = (short)f2bf(a.w);
    o[4] = (short)f2bf(b.x); o[5] = (short)f2bf(b.y);
    o[6] = (short)f2bf(b.z); o[7] = (short)f2bf(b.w);
    *((bf16x8*)out + i) = o;
}

// ---------------------------------------------------------------------------
// W fp32 [K=1024][N=1024] -> WT bf16 [N][K] (transposed), 32x32 LDS tiles
// ---------------------------------------------------------------------------
__global__ __launch_bounds__(256)
void cvt_tr(const float* __restrict__ W, unsigned short* __restrict__ WT)
{
    __shared__ float t[32][33];
    const int x = threadIdx.x, y0 = threadIdx.y;   // 32 x 8
    const int bx = blockIdx.x, by = blockIdx.y;
#pragma unroll
    for (int j = 0; j < 4; ++j)
        t[y0 + j*8][x] = W[(size_t)(by*32 + y0 + j*8) * DIM + bx*32 + x];
    __syncthreads();
#pragma unroll
    for (int j = 0; j < 4; ++j)
        WT[(size_t)(bx*32 + y0 + j*8) * DIM + by*32 + x] = f2bf(t[x][y0 + j*8]);
}

// ---------------------------------------------------------------------------
// GEMM: C[M,N] = A[M,K] @ BT[N,K]^T (+bias). bf16 MFMA 16x16x32.
// 128x128 tile, BK=32, 4 waves (2x2), each wave 64x64 via 4x4 MFMAs.
// LDS tiles [128 rows][32 k] bf16, row = 64B = 4 chunks of 16B,
// chunk swizzle c' = c ^ ((r>>1)&3) -> uniform bank distribution.
// ---------------------------------------------------------------------------
template<bool F32OUT>
__global__ __launch_bounds__(256)
void gemm_bf16(const unsigned short* __restrict__ A, const unsigned short* __restrict__ BT,
               const float* __restrict__ bias, void* __restrict__ Cout,
               const int M, const int N, const int K)
{
    __shared__ unsigned short As[128*32];
    __shared__ unsigned short Bs[128*32];
    const int t = threadIdx.x;
    const int w = t >> 6, lane = t & 63, g = lane >> 4, li = lane & 15;
    const int wm = (w >> 1) * 64, wn = (w & 1) * 64;
    const int m0 = blockIdx.x * 128, n0 = blockIdx.y * 128;

    f32x4 acc[4][4] = {};

    // staging: thread owns chunks (r0, c0) and (r0, c0+1); r0 = t>>1, c0 = (t&1)*2
    const int r0 = t >> 1, c0 = (t & 1) * 2;
    const unsigned short* Ap = &A [(size_t)(m0 + r0) * K + c0*8];
    const unsigned short* Bp = &BT[(size_t)(n0 + r0) * K + c0*8];
    char* AsB = (char*)As;
    char* BsB = (char*)Bs;
    const int sw  = (r0 >> 1) & 3;
    const int wa0 = r0*64 + ((c0       ^ sw) * 16);
    const int wa1 = r0*64 + (((c0 + 1) ^ sw) * 16);

    for (int kt = 0; kt < K; kt += 32) {
        bf16x8 a0 = *(const bf16x8*)(Ap + kt);
        bf16x8 a1 = *(const bf16x8*)(Ap + kt + 8);
        bf16x8 b0 = *(const bf16x8*)(Bp + kt);
        bf16x8 b1 = *(const bf16x8*)(Bp + kt + 8);
        __syncthreads();   // prev frag reads done before overwrite
        *(bf16x8*)(AsB + wa0) = a0;
        *(bf16x8*)(AsB + wa1) = a1;
        *(bf16x8*)(BsB + wa0) = b0;
        *(bf16x8*)(BsB + wa1) = b1;
        __syncthreads();

        bf16x8 af[4], bfv[4];
#pragma unroll
        for (int mi = 0; mi < 4; ++mi) {
            const int r = wm + mi*16 + li;
            af[mi] = *(const bf16x8*)(AsB + r*64 + ((g ^ ((r >> 1) & 3)) * 16));
        }
#pragma unroll
        for (int ni = 0; ni < 4; ++ni) {
            const int r = wn + ni*16 + li;
            bfv[ni] = *(const bf16x8*)(BsB + r*64 + ((g ^ ((r >> 1) & 3)) * 16));
        }
#pragma unroll
        for (int mi = 0; mi < 4; ++mi)
#pragma unroll
            for (int ni = 0; ni < 4; ++ni)
                acc[mi][ni] = __builtin_amdgcn_mfma_f32_16x16x32_bf16(
                    af[mi], bfv[ni], acc[mi][ni], 0, 0, 0);
    }

    // epilogue: D row = 4*g + reg, col = li (per 16x16 tile)
#pragma unroll
    for (int mi = 0; mi < 4; ++mi)
#pragma unroll
        for (int ni = 0; ni < 4; ++ni) {
            const int gr = m0 + wm + mi*16 + 4*g;
            const int gc = n0 + wn + ni*16 + li;
#pragma unroll
            for (int r = 0; r < 4; ++r) {
                const float v = acc[mi][ni][r];
                if (F32OUT)
                    ((float*)Cout)[(size_t)(gr + r) * N + gc] = v + bias[gc];
                else
                    ((unsigned short*)Cout)[(size_t)(gr + r) * N + gc] = f2bf(v);
            }
        }
}

// ---------------------------------------------------------------------------
// Flash attention, bf16 MFMA. Block: 64 q-rows, 4 waves x 16 rows.
// Q frags in registers; K staged natural [kv][d] (== B-operand layout for
// QK^T); V transposed at staging into VT[d][kv]; P via wave-private LDS.
// All LDS tiles [64][64] bf16, row = 128B = 8 chunks, swizzle c' = c^(row&7).
// ---------------------------------------------------------------------------
__global__ __launch_bounds__(256)
void attn_bf16(const unsigned short* __restrict__ Q, const unsigned short* __restrict__ Km,
               const unsigned short* __restrict__ V, unsigned short* __restrict__ O)
{
    __shared__ unsigned short Ks[64*64];
    __shared__ unsigned short VT[64*64];
    __shared__ unsigned short Ps[64*64];
    const int t = threadIdx.x;
    const int w = t >> 6, lane = t & 63, g = lane >> 4, li = lane & 15;
    const int qt = (int)gridDim.x - 1 - (int)blockIdx.x;   // heavy blocks first
    const int bh = blockIdx.y, b = bh >> 4, h = bh & 15;
    const int q0 = qt * 64;
    const size_t rowbase = (size_t)b * TSEQ;
    const int cb = h * HD;

    bf16x8 qa[2];
#pragma unroll
    for (int ks = 0; ks < 2; ++ks)
        qa[ks] = *(const bf16x8*)&Q[(rowbase + q0 + w*16 + li) * DIM + cb + 8*g + 32*ks];

    f32x4 ctx[4] = {};
    float m_i[4], l_i[4];
#pragma unroll
    for (int r = 0; r < 4; ++r) { m_i[r] = -INFINITY; l_i[r] = 0.f; }

    char* KsB = (char*)Ks;
    char* VTB = (char*)VT;
    char* PsB = (char*)Ps;

    for (int kv = 0; kv <= qt; ++kv) {
        __syncthreads();   // prev tile's LDS reads complete
        const size_t kbase = rowbase + kv*64;
        // stage K: 512 chunks, 2/thread; element (r,c): byte r*128 + ((c^(r&7))*16)
#pragma unroll
        for (int i = 0; i < 2; ++i) {
            const int tc = 2*t + i;
            const int r = tc >> 3, c = tc & 7;
            bf16x8 kk = *(const bf16x8*)&Km[(kbase + r) * DIM + cb + c*8];
            *(bf16x8*)(KsB + r*128 + ((c ^ (r & 7)) * 16)) = kk;
        }
        // stage V transposed: thread reads V[kvr][dc*8..+7], scatters to VT[d][kvr]
        const int kvr = t & 63;
#pragma unroll
        for (int i = 0; i < 2; ++i) {
            const int dc = (t >> 6) * 2 + i;
            bf16x8 vv = *(const bf16x8*)&V[(kbase + kvr) * DIM + cb + dc*8];
#pragma unroll
            for (int j = 0; j < 8; ++j) {
                const int d = dc*8 + j;
                *(unsigned short*)(VTB + d*128 + (((kvr >> 3) ^ (d & 7)) * 16)
                                   + (kvr & 7) * 2) = (unsigned short)vv[j];
            }
        }
        __syncthreads();

        // S = Q K^T : per wave 16x64 strip, 4 nt x 2 ks MFMAs
        f32x4 s[4] = {};
#pragma unroll
        for (int nt = 0; nt < 4; ++nt) {
            const int r = nt*16 + li;
#pragma unroll
            for (int ks = 0; ks < 2; ++ks) {
                bf16x8 kb = *(const bf16x8*)(KsB + r*128 + (((g + 4*ks) ^ (r & 7)) * 16));
                s[nt] = __builtin_amdgcn_mfma_f32_16x16x32_bf16(qa[ks], kb, s[nt], 0, 0, 0);
            }
        }
#pragma unroll
        for (int nt = 0; nt < 4; ++nt) s[nt] *= 0.125f;   // 1/sqrt(64)
        if (kv == qt) {   // diagonal: mask kv_local > q_local
#pragma unroll
            for (int nt = 0; nt < 4; ++nt) {
                const int kvl = nt*16 + li;
#pragma unroll
                for (int r = 0; r < 4; ++r)
                    if (kvl > w*16 + 4*g + r) s[nt][r] = -INFINITY;
            }
        }

        // online softmax; D rows: q = w*16 + 4*g + r; cols across (li, nt)
#pragma unroll
        for (int r = 0; r < 4; ++r) {
            float mx = fmaxf(fmaxf(s[0][r], s[1][r]), fmaxf(s[2][r], s[3][r]));
            mx = fmaxf(mx, __shfl_xor(mx, 1));
            mx = fmaxf(mx, __shfl_xor(mx, 2));
            mx = fmaxf(mx, __shfl_xor(mx, 4));
            mx = fmaxf(mx, __shfl_xor(mx, 8));
            const float mnew = fmaxf(m_i[r], mx);
            const float sc = __expf(m_i[r] - mnew);
            const float p0 = __expf(s[0][r] - mnew), p1 = __expf(s[1][r] - mnew);
            const float p2 = __expf(s[2][r] - mnew), p3 = __expf(s[3][r] - mnew);
            float rs = p0 + p1 + p2 + p3;
            rs += __shfl_xor(rs, 1);
            rs += __shfl_xor(rs, 2);
            rs += __shfl_xor(rs, 4);
            rs += __shfl_xor(rs, 8);
            l_i[r] = l_i[r]*sc + rs;
            m_i[r] = mnew;
#pragma unroll
            for (int n2 = 0; n2 < 4; ++n2) ctx[n2][r] *= sc;
            const int q = w*16 + 4*g + r;
            const int ch = li >> 3, cl = (li & 7)*2, qs = q & 7;
            *(unsigned short*)(PsB + q*128 + (((0 + ch) ^ qs)*16) + cl) = f2bf(p0);
            *(unsigned short*)(PsB + q*128 + (((2 + ch) ^ qs)*16) + cl) = f2bf(p1);
            *(unsigned short*)(PsB + q*128 + (((4 + ch) ^ qs)*16) + cl) = f2bf(p2);
            *(unsigned short*)(PsB + q*128 + (((6 + ch) ^ qs)*16) + cl) = f2bf(p3);
        }

        // PV: Ps strip is wave-private -> no barrier needed (in-order wave LDS)
        bf16x8 pa[2];
#pragma unroll
        for (int ks = 0; ks < 2; ++ks) {
            const int r = w*16 + li;
            pa[ks] = *(const bf16x8*)(PsB + r*128 + (((g + 4*ks) ^ (r & 7)) * 16));
        }
#pragma unroll
        for (int n2 = 0; n2 < 4; ++n2) {
            const int r = n2*16 + li;
#pragma unroll
            for (int ks = 0; ks < 2; ++ks) {
                bf16x8 vb = *(const bf16x8*)(VTB + r*128 + (((g + 4*ks) ^ (r & 7)) * 16));
                ctx[n2] = __builtin_amdgcn_mfma_f32_16x16x32_bf16(pa[ks], vb, ctx[n2], 0, 0, 0);
            }
        }
    }

    // normalize + write bf16 ctx
#pragma unroll
    for (int r = 0; r < 4; ++r) {
        const float inv = 1.f / l_i[r];
        const size_t row = rowbase + q0 + w*16 + 4*g + r;
#pragma unroll
        for (int n2 = 0; n2 < 4; ++n2)
            O[row * DIM + cb + n2*16 + li] = f2bf(ctx[n2][r] * inv);
    }
}

// ---------------------------------------------------------------------------
extern "C" void kernel_launch(void* const* d_in, const int* in_sizes, int n_in,
                              void* d_out, int out_size, void* d_ws, size_t ws_size,
                              hipStream_t stream)
{
    const float* x  = (const float*)d_in[0];
    const float* Wq = (const float*)d_in[1];
    const float* Wk = (const float*)d_in[2];
    const float* Wv = (const float*)d_in[3];
    const float* Wo = (const float*)d_in[4];
    const float* bo = (const float*)d_in[5];
    float* out = (float*)d_out;

    char* ws = (char*)d_ws;
    unsigned short* xb  = (unsigned short*)(ws);                      // 16 MB
    unsigned short* qb  = (unsigned short*)(ws + (16u << 20));        // 16 MB
    unsigned short* kb  = (unsigned short*)(ws + (32u << 20));        // 16 MB
    unsigned short* vb  = (unsigned short*)(ws + (48u << 20));        // 16 MB
    unsigned short* ctb = (unsigned short*)(ws + (64u << 20));        // 16 MB
    unsigned short* WqT = (unsigned short*)(ws + (80u << 20));        // 2 MB
    unsigned short* WkT = (unsigned short*)(ws + (82u << 20));
    unsigned short* WvT = (unsigned short*)(ws + (84u << 20));
    unsigned short* WoT = (unsigned short*)(ws + (86u << 20));        // ends 88 MB

    cvt_x<<<MTOT*DIM/8/256, 256, 0, stream>>>(x, xb, MTOT*DIM/8);
    dim3 tb(32, 8), tg(32, 32);
    cvt_tr<<<tg, tb, 0, stream>>>(Wq, WqT);
    cvt_tr<<<tg, tb, 0, stream>>>(Wk, WkT);
    cvt_tr<<<tg, tb, 0, stream>>>(Wv, WvT);
    cvt_tr<<<tg, tb, 0, stream>>>(Wo, WoT);

    dim3 gg(MTOT/128, DIM/128);
    gemm_bf16<false><<<gg, 256, 0, stream>>>(xb, WqT, nullptr, qb, MTOT, DIM, DIM);
    gemm_bf16<false><<<gg, 256, 0, stream>>>(xb, WkT, nullptr, kb, MTOT, DIM, DIM);
    gemm_bf16<false><<<gg, 256, 0, stream>>>(xb, WvT, nullptr, vb, MTOT, DIM, DIM);

    attn_bf16<<<dim3(TSEQ/64, BATCH*NH), 256, 0, stream>>>(qb, kb, vb, ctb);

    gemm_bf16<true><<<gg, 256, 0, stream>>>(ctb, WoT, bo, out, MTOT, DIM, DIM);
}